// Round 8
// baseline (260.577 us; speedup 1.0000x reference)
//
#include <hip/hip_runtime.h>

#define WIDTH  1024
#define HEIGHT 1024
#define R      4            // rows per block; HEIGHT % R == 0 so blocks never straddle images

typedef float vfloat4 __attribute__((ext_vector_type(4)));

__global__ __launch_bounds__(256, 2) void fdtd_kernel(
    const float* __restrict__ u1,
    const float* __restrict__ u0,
    const float* __restrict__ j2,
    const float* __restrict__ j0,
    float* __restrict__ out,
    int chunk)                              // gridDim.x / 8 (0 => no swizzle)
{
    // XCD-aware chunked swizzle (kept from R5 config).
    const int bid = blockIdx.x;
    const int swz = chunk ? ((bid & 7) * chunk + (bid >> 3)) : bid;

    const int y0 = swz * R;                 // first computed global row
    const int iy = y0 & (HEIGHT - 1);       // row within image (block fully inside one image)
    const int x0 = threadIdx.x << 2;        // 4 floats/thread, full 1024-wide row per block
    const long base = (long)y0 * WIDTH + x0;

    // ---- branch-free halo addressing: clamped (in-bounds) offsets + 0/1 masks ----
    const long  upOff  = (iy > 0)          ? -(long)WIDTH     : 0;
    const long  dnOff  = (iy + R < HEIGHT) ? (long)R * WIDTH  : (long)(R - 1) * WIDTH;
    const float upMask = (iy > 0)          ? 1.0f : 0.0f;
    const float dnMask = (iy + R < HEIGHT) ? 1.0f : 0.0f;
    const long  lfOff  = (x0 > 0)          ? -1L : 0L;
    const long  rtOff  = (x0 + 4 < WIDTH)  ?  4L : 3L;
    const float lfMask = (x0 > 0)          ? 1.0f : 0.0f;
    const float rtMask = (x0 + 4 < WIDTH)  ? 1.0f : 0.0f;

    // ---- phase 1: issue ALL loads — EVERY load nontemporal (no L2/L3 allocation).
    // Theory: the Infinity-Cache read path is a ~1.75 TB/s server; forcing all input
    // traffic to the 6.3 TB/s HBM path (no cache residency next dispatch) is faster.
    vfloat4 ctop, c[R], cbot, a0[R], v2[R], v0[R];
    float lf[R], rt[R];

    ctop = __builtin_nontemporal_load((const vfloat4*)(u1 + base + upOff));
#pragma unroll
    for (int r = 0; r < R; ++r)
        c[r] = __builtin_nontemporal_load((const vfloat4*)(u1 + base + (long)r * WIDTH));
    cbot = __builtin_nontemporal_load((const vfloat4*)(u1 + base + dnOff));

#pragma unroll
    for (int r = 0; r < R; ++r) {
        const long b = base + (long)r * WIDTH;
        lf[r] = __builtin_nontemporal_load(u1 + b + lfOff);
        rt[r] = __builtin_nontemporal_load(u1 + b + rtOff);
        a0[r] = __builtin_nontemporal_load((const vfloat4*)(u0 + b));
        v2[r] = __builtin_nontemporal_load((const vfloat4*)(j2 + b));
        v0[r] = __builtin_nontemporal_load((const vfloat4*)(j0 + b));
    }

    // ---- phase 2: compute + store (NT stores kept — best known config) ----
#pragma unroll
    for (int r = 0; r < R; ++r) {
        const vfloat4 up = (r == 0)     ? (vfloat4)(ctop * upMask) : c[r - 1];
        const vfloat4 dn = (r == R - 1) ? (vfloat4)(cbot * dnMask) : c[r + 1];
        const vfloat4 ce = c[r];
        const float lfv = lf[r] * lfMask;
        const float rtv = rt[r] * rtMask;

        vfloat4 o;
        o.x = 2.0f * ce.x - a0[r].x + 0.25f * (up.x + dn.x + lfv  + ce.y - 4.0f * ce.x)
            - 0.0025f * (v2[r].x - v0[r].x);
        o.y = 2.0f * ce.y - a0[r].y + 0.25f * (up.y + dn.y + ce.x + ce.z - 4.0f * ce.y)
            - 0.0025f * (v2[r].y - v0[r].y);
        o.z = 2.0f * ce.z - a0[r].z + 0.25f * (up.z + dn.z + ce.y + ce.w - 4.0f * ce.z)
            - 0.0025f * (v2[r].z - v0[r].z);
        o.w = 2.0f * ce.w - a0[r].w + 0.25f * (up.w + dn.w + ce.z + rtv  - 4.0f * ce.w)
            - 0.0025f * (v2[r].w - v0[r].w);
        __builtin_nontemporal_store(o, (vfloat4*)(out + base + (long)r * WIDTH));
    }
}

extern "C" void kernel_launch(void* const* d_in, const int* in_sizes, int n_in,
                              void* d_out, int out_size, void* d_ws, size_t ws_size,
                              hipStream_t stream) {
    const float* u1 = (const float*)d_in[0];
    const float* u0 = (const float*)d_in[1];
    const float* j2 = (const float*)d_in[2];
    const float* j0 = (const float*)d_in[3];
    float* out = (float*)d_out;

    const int nrows   = out_size / WIDTH;   // B*H = 16384 (out_size is element count)
    const int nblocks = nrows / R;          // 4096
    const int chunk   = (nblocks % 8 == 0) ? (nblocks >> 3) : 0;

    dim3 block(WIDTH / 4);                  // 256 threads: one full row per block-row
    dim3 grid(nblocks);
    fdtd_kernel<<<grid, block, 0, stream>>>(u1, u0, j2, j0, out, chunk);
}